// Round 17
// baseline (360.449 us; speedup 1.0000x reference)
//
#include <hip/hip_runtime.h>
#include <hip/hip_fp16.h>

typedef _Float16 f16x8 __attribute__((ext_vector_type(8)));  // 8 fp16 = 4 VGPRs (MFMA A/B)
typedef float fx4 __attribute__((ext_vector_type(4)));       // MFMA acc

#define AS_G(p) ((const __attribute__((address_space(1))) void*)(p))
#define AS_L(p) ((__attribute__((address_space(3))) void*)(p))

struct __align__(8) half4 { __half2 lo, hi; };
struct __align__(8) edge_t { int u; float w; };   // paired edge record: one 8B store/load

// fp16 two-term split for weights: hi = fp16(w), lo = fp16(w - hi)  (combined ~2^-23 rel)
__device__ inline void split2h(float a, __half& hi, __half& lo) {
    hi = __float2half(a);
    lo = __float2half(a - __half2float(hi));
}

// ===================== graph preprocessing =====================

// fused dispatch: blocks [0,degB) histogram degrees (8 edges/thread); blocks [degB,..) x -> fp16.
__global__ void k_degx(const int* __restrict__ dst, int E, int* __restrict__ deg, int degB,
                       const float* __restrict__ x, __half* __restrict__ xh, int nx) {
    if (blockIdx.x < (unsigned)degB) {
        int i = (blockIdx.x * 256 + threadIdx.x) * 8;
        if (i + 8 <= E) {
            int4 d0 = *(const int4*)&dst[i];
            int4 d1 = *(const int4*)&dst[i + 4];
            atomicAdd(&deg[d0.x], 1); atomicAdd(&deg[d0.y], 1);
            atomicAdd(&deg[d0.z], 1); atomicAdd(&deg[d0.w], 1);
            atomicAdd(&deg[d1.x], 1); atomicAdd(&deg[d1.y], 1);
            atomicAdd(&deg[d1.z], 1); atomicAdd(&deg[d1.w], 1);
        } else {
            for (int j = i; j < E; ++j) atomicAdd(&deg[dst[j]], 1);
        }
    } else {
        int i = (blockIdx.x - degB) * 1024 + threadIdx.x * 4;
        if (i < nx) {
            float4 v = *(const float4*)&x[i];
            __half2 h0(__float2half(v.x), __float2half(v.y));
            __half2 h1(__float2half(v.z), __float2half(v.w));
            *(__half2*)&xh[i] = h0;
            *(__half2*)&xh[i + 2] = h1;
        }
    }
}

// fused dispatch: blocks [0,nb) deg-scan + dinv; blocks [nb,..) split/transpose weights to fp16 hi/lo.
__global__ void k_scan1w(const int* __restrict__ deg, int N, int nb,
                         int* __restrict__ part, int* __restrict__ bsum, float* __restrict__ dinv,
                         const float* __restrict__ W0, __half* __restrict__ h0, __half* __restrict__ l0,
                         const float* __restrict__ W1, __half* __restrict__ h1, __half* __restrict__ l1,
                         const float* __restrict__ W2, __half* __restrict__ h2, __half* __restrict__ l2,
                         int DIN, int DH) {
    __shared__ int s[256];
    if (blockIdx.x < (unsigned)nb) {
        int i = blockIdx.x * 256 + threadIdx.x;
        int v = (i < N) ? deg[i] : 0;
        if (i < N) dinv[i] = 1.0f / sqrtf((float)(v + 1));  // +1 self-loop
        s[threadIdx.x] = v;
        __syncthreads();
        for (int off = 1; off < 256; off <<= 1) {
            int t = (threadIdx.x >= off) ? s[threadIdx.x - off] : 0;
            __syncthreads();
            s[threadIdx.x] += t;
            __syncthreads();
        }
        if (i < N) part[i] = s[threadIdx.x] - v;
        if (threadIdx.x == 255) bsum[blockIdx.x] = s[255];
    } else {
        int i = (blockIdx.x - nb) * 256 + threadIdx.x;
        const int n0 = DIN * DH, n1 = DH * DH;
        const float* W; __half *hT, *lT; int K, li;
        if (i < n0) { W = W0; hT = h0; lT = l0; K = DIN; li = i; }
        else if (i < n0 + n1) { W = W1; hT = h1; lT = l1; K = DH; li = i - n0; }
        else if (i < n0 + 2 * n1) { W = W2; hT = h2; lT = l2; K = DH; li = i - n0 - n1; }
        else return;
        int k = li / DH, n = li - k * DH;
        __half h, l;
        split2h(W[li], h, l);
        hT[(size_t)n * K + k] = h;
        lT[(size_t)n * K + k] = l;
    }
}

// rowptr build; each block reduces the raw per-block sums itself (nb <= 256).
__global__ void k_scan3(const int* __restrict__ part, const int* __restrict__ bsum, int nb,
                        int N, int E, int* __restrict__ rowptr, int* __restrict__ cursor) {
    __shared__ int s[256];
    const int t = threadIdx.x;
    s[t] = (t < nb && t < (int)blockIdx.x) ? bsum[t] : 0;
    __syncthreads();
    for (int off = 128; off > 0; off >>= 1) {
        if (t < off) s[t] += s[t + off];
        __syncthreads();
    }
    const int base = s[0];
    int i = blockIdx.x * 256 + t;
    if (i < N) {
        int v = part[i] + base;
        rowptr[i] = v;
        cursor[i] = v;
    }
    if (i == 0) rowptr[N] = E;
}

// CSR fill, 2 edges/thread (halves wave count of this atomic-bound pass).
__global__ void k_fill(const int* __restrict__ src, const int* __restrict__ dst, int E,
                       const float* __restrict__ dinv, int* __restrict__ cursor,
                       edge_t* __restrict__ edg) {
    int e = (blockIdx.x * blockDim.x + threadIdx.x) * 2;
    if (e + 2 <= E) {
        int2 s2 = *(const int2*)&src[e];
        int2 d2 = *(const int2*)&dst[e];
        int p0 = atomicAdd(&cursor[d2.x], 1);
        edge_t e0; e0.u = s2.x; e0.w = dinv[s2.x] * dinv[d2.x];
        edg[p0] = e0;
        int p1 = atomicAdd(&cursor[d2.y], 1);
        edge_t e1; e1.u = s2.y; e1.w = dinv[s2.y] * dinv[d2.y];
        edg[p1] = e1;
    } else {
        for (int j = e; j < E; ++j) {
            int s = src[j], d = dst[j];
            int p = atomicAdd(&cursor[d], 1);
            edge_t ed; ed.u = s; ed.w = dinv[s] * dinv[d];
            edg[p] = ed;
        }
    }
}

// ===================== fp16 MFMA GEMM, BN=256 (full output width per block) =============
// Block = 128 rows x 256 cols, 512 threads (8 waves, 2x4 grid of 64x64 wave tiles).
// A fetched once/layer. LDS 40KB -> 4 blocks/CU. Single-buffered (r13: dbuf neutral).

__device__ __forceinline__ void gemm_core(
    const __half* __restrict__ Aop, const __half* __restrict__ BhiT, const __half* __restrict__ BloT,
    __half* smem, int Nrows, int K, int row0,
    int wid, int lane, int wrow, int wcol, int quad, int l16, fx4 (&acc)[4][4]) {
    const __half* gp[5];
    int ldsoff[5];
#pragma unroll
    for (int j = 0; j < 5; ++j) {
        int L = wid * 5 + j;
        int arr, slot;
        if (L < 8) { arr = 0; slot = L; }
        else if (L < 24) { arr = 1; slot = L - 8; }
        else { arr = 2; slot = L - 24; }
        int r = 16 * slot + (lane >> 2);
        int s = lane & 3;
        int q = (s - (r >> 1)) & 3;              // XOR swizzle folded into global addr
        const __half* garr = (arr == 0) ? Aop : (arr == 1) ? BhiT : BloT;
        int grow = (arr == 0) ? min(row0 + r, Nrows - 1) : r;
        gp[j] = garr + (size_t)grow * K + q * 8;
        ldsoff[j] = ((arr == 0) ? 0 : (arr == 1) ? 8192 : 24576) + slot * 1024;
    }

    const __half* sA   = smem;                   // 128 x 32
    const __half* sBhi = smem + 4096;            // 256 x 32
    const __half* sBlo = smem + 12288;           // 256 x 32

    int aidx[4], bidx[4];
#pragma unroll
    for (int t = 0; t < 4; ++t) {
        int ra = wrow * 64 + t * 16 + l16;
        aidx[t] = ra * 32 + ((quad + (ra >> 1)) & 3) * 8;
        int rb = wcol * 64 + t * 16 + l16;
        bidx[t] = rb * 32 + ((quad + (rb >> 1)) & 3) * 8;
    }

    for (int k0 = 0; k0 < K; k0 += 32) {
#pragma unroll
        for (int j = 0; j < 5; ++j)
            __builtin_amdgcn_global_load_lds(AS_G(gp[j] + k0), AS_L((char*)smem + ldsoff[j]), 16, 0, 0);
        __syncthreads();

        f16x8 a[4];
#pragma unroll
        for (int mi = 0; mi < 4; ++mi) a[mi] = *(const f16x8*)&sA[aidx[mi]];
#pragma unroll
        for (int nj = 0; nj < 4; ++nj) {
            f16x8 bh = *(const f16x8*)&sBhi[bidx[nj]];
            f16x8 bl = *(const f16x8*)&sBlo[bidx[nj]];
#pragma unroll
            for (int mi = 0; mi < 4; ++mi) {
                acc[mi][nj] = __builtin_amdgcn_mfma_f32_16x16x32_f16(a[mi], bh, acc[mi][nj], 0, 0, 0);
                acc[mi][nj] = __builtin_amdgcn_mfma_f32_16x16x32_f16(a[mi], bl, acc[mi][nj], 0, 0, 0);
            }
        }
        __syncthreads();
    }
}

__global__ __launch_bounds__(512) void k_gemm_mfma(
    const __half* __restrict__ Aop, const __half* __restrict__ BhiT, const __half* __restrict__ BloT,
    const float* __restrict__ bias, __half* __restrict__ C, int Nrows, int K) {
    __shared__ __align__(16) __half smem[20480];   // 40 KB
    const int tid = threadIdx.x;
    const int wid = tid >> 6, lane = tid & 63;
    const int row0 = blockIdx.x * 128;
    const int wrow = wid & 1, wcol = wid >> 1;
    const int quad = lane >> 4, l16 = lane & 15;

    fx4 acc[4][4] = {};
    gemm_core(Aop, BhiT, BloT, smem, Nrows, K, row0, wid, lane, wrow, wcol, quad, l16, acc);

    // C/D layout: col = lane&15, row = quad*4 + reg  [m89-verified]
#pragma unroll
    for (int mi = 0; mi < 4; ++mi) {
        const int rbase = row0 + wrow * 64 + mi * 16 + quad * 4;
#pragma unroll
        for (int nj = 0; nj < 4; ++nj) {
            const int c = wcol * 64 + nj * 16 + l16;
            const float bc = bias[c];
#pragma unroll
            for (int reg = 0; reg < 4; ++reg) {
                int r = rbase + reg;
                if (r < Nrows) C[(size_t)r * 256 + c] = __float2half(fmaxf(acc[mi][nj][reg] + bc, 0.f));
            }
        }
    }
}

// Layer-2 variant: relu(acc+bias) pooled per-graph into gsum[64][256]
__global__ __launch_bounds__(512) void k_gemm_pool(
    const __half* __restrict__ Aop, const __half* __restrict__ BhiT, const __half* __restrict__ BloT,
    const float* __restrict__ bias, const int* __restrict__ batch,
    float* __restrict__ gsum, int Nrows, int K) {
    __shared__ __align__(16) __half smem[20480];
    const int tid = threadIdx.x;
    const int wid = tid >> 6, lane = tid & 63;
    const int row0 = blockIdx.x * 128;
    const int wrow = wid & 1, wcol = wid >> 1;
    const int quad = lane >> 4, l16 = lane & 15;

    fx4 acc[4][4] = {};
    gemm_core(Aop, BhiT, BloT, smem, Nrows, K, row0, wid, lane, wrow, wcol, quad, l16, acc);

    int bg[4][4];
#pragma unroll
    for (int mi = 0; mi < 4; ++mi)
#pragma unroll
        for (int reg = 0; reg < 4; ++reg) {
            int r = row0 + wrow * 64 + mi * 16 + quad * 4 + reg;
            bg[mi][reg] = (r < Nrows) ? batch[r] : -1;
        }
    const int gfirst = batch[row0 < Nrows ? row0 : (Nrows - 1)];
    const int glast  = batch[min(row0 + 127, Nrows - 1)];

#pragma unroll
    for (int nj = 0; nj < 4; ++nj) {
        const int c = wcol * 64 + nj * 16 + l16;
        const float bc = bias[c];
        for (int g = gfirst; g <= glast; ++g) {
            float s = 0.f;
#pragma unroll
            for (int mi = 0; mi < 4; ++mi)
#pragma unroll
                for (int reg = 0; reg < 4; ++reg)
                    if (bg[mi][reg] == g) s += fmaxf(acc[mi][nj][reg] + bc, 0.f);
            s += __shfl_xor(s, 16);
            s += __shfl_xor(s, 32);
            if (quad == 0) atomicAdd(&gsum[g * 256 + c], s);
        }
    }
}

// ===================== aggregation (fp16 gather, fp32 accumulate, fp16 out) =============
// WAVE-PER-NODE; edge-batch software prefetch: next batch's 8B edge records load while
// current batch's gathers are outstanding (breaks the edge-load -> gather serial chain).
// FMA order per node unchanged (bit-stable given same edge permutation).

__global__ __launch_bounds__(256) void k_agg256(const __half* __restrict__ H, const int* __restrict__ rowptr,
                                                const edge_t* __restrict__ edg,
                                                const float* __restrict__ dinv,
                                                __half* __restrict__ outA, int N) {
    const int wave = threadIdx.x >> 6, lane = threadIdx.x & 63;
    const int v = blockIdx.x * 4 + wave;
    if (v >= N) return;

    const float di = dinv[v];
    const float selfn = di * di;
    half4 hv = ((const half4*)&H[(size_t)v * 256])[lane];
    float2 s0 = __half22float2(hv.lo), s1 = __half22float2(hv.hi);
    float ax = selfn * s0.x, ay = selfn * s0.y, az = selfn * s1.x, aw = selfn * s1.y;

    int e = rowptr[v];
    const int end = rowptr[v + 1];
    int nb8 = (end - e) >> 3;

    edge_t edc[8];
    if (nb8 > 0) {
#pragma unroll
        for (int j = 0; j < 8; ++j) edc[j] = edg[e + j];
    }
    for (int b = 0; b < nb8; ++b) {
        edge_t edn[8];
        const bool more = (b + 1 < nb8);
        if (more) {
#pragma unroll
            for (int j = 0; j < 8; ++j) edn[j] = edg[e + 8 + j];
        }
        half4 g[8];
#pragma unroll
        for (int j = 0; j < 8; ++j) g[j] = ((const half4*)&H[(size_t)edc[j].u * 256])[lane];
#pragma unroll
        for (int j = 0; j < 8; ++j) {
            float2 f0 = __half22float2(g[j].lo), f1 = __half22float2(g[j].hi);
            ax += edc[j].w * f0.x; ay += edc[j].w * f0.y; az += edc[j].w * f1.x; aw += edc[j].w * f1.y;
        }
        if (more) {
#pragma unroll
            for (int j = 0; j < 8; ++j) edc[j] = edn[j];
        }
        e += 8;
    }
    for (; e < end; ++e) {
        edge_t ed = edg[e];
        half4 g = ((const half4*)&H[(size_t)ed.u * 256])[lane];
        float2 f0 = __half22float2(g.lo), f1 = __half22float2(g.hi);
        ax += ed.w * f0.x; ay += ed.w * f0.y; az += ed.w * f1.x; aw += ed.w * f1.y;
    }

    half4 o;
    o.lo = __floats2half2_rn(ax, ay);
    o.hi = __floats2half2_rn(az, aw);
    ((half4*)outA)[(size_t)v * 64 + lane] = o;
}

__global__ __launch_bounds__(256) void k_agg128(const __half* __restrict__ X, const int* __restrict__ rowptr,
                                                const edge_t* __restrict__ edg,
                                                const float* __restrict__ dinv,
                                                __half* __restrict__ outA, int N) {
    const int half = threadIdx.x >> 5, sub = threadIdx.x & 31;
    const int v = blockIdx.x * 8 + half;
    if (v >= N) return;

    const float di = dinv[v];
    const float selfn = di * di;
    half4 hv = ((const half4*)&X[(size_t)v * 128])[sub];
    float2 s0 = __half22float2(hv.lo), s1 = __half22float2(hv.hi);
    float ax = selfn * s0.x, ay = selfn * s0.y, az = selfn * s1.x, aw = selfn * s1.y;

    int e = rowptr[v];
    const int end = rowptr[v + 1];
    for (; e + 4 <= end; e += 4) {
        edge_t ed[4]; half4 g[4];
#pragma unroll
        for (int j = 0; j < 4; ++j) ed[j] = edg[e + j];
#pragma unroll
        for (int j = 0; j < 4; ++j) g[j] = ((const half4*)&X[(size_t)ed[j].u * 128])[sub];
#pragma unroll
        for (int j = 0; j < 4; ++j) {
            float2 f0 = __half22float2(g[j].lo), f1 = __half22float2(g[j].hi);
            ax += ed[j].w * f0.x; ay += ed[j].w * f0.y; az += ed[j].w * f1.x; aw += ed[j].w * f1.y;
        }
    }
    for (; e < end; ++e) {
        edge_t ed = edg[e];
        half4 g = ((const half4*)&X[(size_t)ed.u * 128])[sub];
        float2 f0 = __half22float2(g.lo), f1 = __half22float2(g.hi);
        ax += ed.w * f0.x; ay += ed.w * f0.y; az += ed.w * f1.x; aw += ed.w * f1.y;
    }

    half4 o;
    o.lo = __floats2half2_rn(ax, ay);
    o.hi = __floats2half2_rn(az, aw);
    ((half4*)outA)[(size_t)v * 32 + sub] = o;
}

// ===================== fused mean-pool finalize + classifier head =====================

__global__ __launch_bounds__(256) void k_poolcls(const float* __restrict__ gsum, const int* __restrict__ batch,
                                                 int N,
                                                 const float* __restrict__ Wc1, const float* __restrict__ bc1,
                                                 const float* __restrict__ Wc2, const float* __restrict__ bc2,
                                                 float* __restrict__ out) {
    __shared__ float sg[256], sh[256];
    __shared__ int bounds[2];
    const int b = blockIdx.x, t = threadIdx.x;
    if (t < 2) {
        int target = b + t;
        int lo = 0, hi = N;
        while (lo < hi) {
            int mid = (lo + hi) >> 1;
            if (batch[mid] < target) lo = mid + 1; else hi = mid;
        }
        bounds[t] = lo;
    }
    __syncthreads();
    const float c = (float)(bounds[1] - bounds[0]);
    sg[t] = gsum[b * 256 + t] / fmaxf(c, 1.0f);
    __syncthreads();
    float acc = bc1[t];
    for (int k = 0; k < 256; ++k) acc += sg[k] * Wc1[k * 256 + t];
    sh[t] = fmaxf(acc, 0.f);
    __syncthreads();
    if (t < 5) {
        float o = bc2[t];
        for (int k = 0; k < 256; ++k) o += sh[k] * Wc2[k * 5 + t];
        out[b * 5 + t] = o;
    }
}

// ===================== launch =====================

extern "C" void kernel_launch(void* const* d_in, const int* in_sizes, int n_in,
                              void* d_out, int out_size, void* d_ws, size_t ws_size,
                              hipStream_t stream) {
    const float* x    = (const float*)d_in[0];
    const int*   eidx = (const int*)d_in[1];
    const int*   batch= (const int*)d_in[2];
    const float* W0 = (const float*)d_in[3];  const float* b0 = (const float*)d_in[4];
    const float* W1 = (const float*)d_in[5];  const float* b1 = (const float*)d_in[6];
    const float* W2 = (const float*)d_in[7];  const float* b2 = (const float*)d_in[8];
    const float* Wc1= (const float*)d_in[9];  const float* bc1= (const float*)d_in[10];
    const float* Wc2= (const float*)d_in[11]; const float* bc2= (const float*)d_in[12];
    float* out = (float*)d_out;

    const int N   = in_sizes[2];       // 50000
    const int E   = in_sizes[1] / 2;   // 500000
    const int DIN = in_sizes[0] / N;   // 128
    const int DH  = in_sizes[4];       // 256
    const int* src = eidx;
    const int* dst = eidx + E;

    char* p = (char*)d_ws;
    auto alloc = [&](size_t bytes) {
        char* r = p;
        p += (bytes + 255) & ~(size_t)255;
        return (void*)r;
    };
    __half* hbuf = (__half*)alloc((size_t)N * DH * 2);   // gemm out (fp16), agg gather in
    __half* ha   = (__half*)alloc((size_t)N * DH * 2);   // agg out / gemm A in (fp16)
    __half* xh   = (__half*)alloc((size_t)N * DIN * 2);  // x in fp16
    __half* w0hi = (__half*)alloc((size_t)DH * DIN * 2);
    __half* w0lo = (__half*)alloc((size_t)DH * DIN * 2);
    __half* w1hi = (__half*)alloc((size_t)DH * DH * 2);
    __half* w1lo = (__half*)alloc((size_t)DH * DH * 2);
    __half* w2hi = (__half*)alloc((size_t)DH * DH * 2);
    __half* w2lo = (__half*)alloc((size_t)DH * DH * 2);
    int*   deg   = (int*)alloc((size_t)N * 4);
    float* gsum  = (float*)alloc(64 * (size_t)DH * 4);   // adjacent to deg: one memset covers both
    float* dinv  = (float*)alloc((size_t)N * 4);
    int*   part  = (int*)alloc((size_t)N * 4);
    int*   bsum  = (int*)alloc(256 * 4);
    int*   rowptr= (int*)alloc((size_t)(N + 1) * 4);
    int*   cursor= (int*)alloc((size_t)N * 4);
    edge_t* edg  = (edge_t*)alloc((size_t)E * 8);

    hipMemsetAsync(deg, 0, (size_t)((char*)gsum - (char*)deg) + 64 * (size_t)DH * 4, stream);

    const int nb = (N + 255) / 256;
    const int wtot = DIN * DH + 2 * DH * DH;
    const int wb = (wtot + 255) / 256;
    const int degB = (E + 2047) / 2048;
    const int nx = N * DIN;
    const int xb = (nx + 1023) / 1024;

    k_degx  <<<degB + xb, 256, 0, stream>>>(dst, E, deg, degB, x, xh, nx);
    k_scan1w<<<nb + wb, 256, 0, stream>>>(deg, N, nb, part, bsum, dinv,
                                          W0, w0hi, w0lo, W1, w1hi, w1lo, W2, w2hi, w2lo, DIN, DH);
    k_scan3 <<<nb, 256, 0, stream>>>(part, bsum, nb, N, E, rowptr, cursor);
    k_fill  <<<(E / 2 + 255) / 256, 256, 0, stream>>>(src, dst, E, dinv, cursor, edg);

    const int gemmBlocks = (N + 127) / 128;

    // layer 0: agg(x fp16) -> fp16 A -> gemm(relu(.W0+b0)) -> fp16 H
    k_agg128<<<(N + 7) / 8, 256, 0, stream>>>(xh, rowptr, edg, dinv, ha, N);
    k_gemm_mfma<<<gemmBlocks, 512, 0, stream>>>(ha, w0hi, w0lo, b0, hbuf, N, DIN);
    // layer 1
    k_agg256<<<(N + 3) / 4, 256, 0, stream>>>(hbuf, rowptr, edg, dinv, ha, N);
    k_gemm_mfma<<<gemmBlocks, 512, 0, stream>>>(ha, w1hi, w1lo, b1, hbuf, N, DH);
    // layer 2 (fused pooling epilogue)
    k_agg256<<<(N + 3) / 4, 256, 0, stream>>>(hbuf, rowptr, edg, dinv, ha, N);
    k_gemm_pool<<<gemmBlocks, 512, 0, stream>>>(ha, w2hi, w2lo, b2, batch, gsum, N, DH);

    k_poolcls<<<64, 256, 0, stream>>>(gsum, batch, N, Wc1, bc1, Wc2, bc2, out);
}

// Round 18
// 340.341 us; speedup vs baseline: 1.0591x; 1.0591x over previous
//
#include <hip/hip_runtime.h>
#include <hip/hip_fp16.h>

typedef _Float16 f16x8 __attribute__((ext_vector_type(8)));  // 8 fp16 = 4 VGPRs (MFMA A/B)
typedef float fx4 __attribute__((ext_vector_type(4)));       // MFMA acc

#define AS_G(p) ((const __attribute__((address_space(1))) void*)(p))
#define AS_L(p) ((__attribute__((address_space(3))) void*)(p))

struct __align__(8) half4 { __half2 lo, hi; };
struct __align__(8) edge_t { int u; float w; };   // paired edge record: one 8B store/load

// fp16 two-term split for weights: hi = fp16(w), lo = fp16(w - hi)  (combined ~2^-23 rel)
__device__ inline void split2h(float a, __half& hi, __half& lo) {
    hi = __float2half(a);
    lo = __float2half(a - __half2float(hi));
}

// ===================== graph preprocessing =====================

// fused dispatch: blocks [0,degB) histogram degrees (8 edges/thread); blocks [degB,..) x -> fp16.
__global__ void k_degx(const int* __restrict__ dst, int E, int* __restrict__ deg, int degB,
                       const float* __restrict__ x, __half* __restrict__ xh, int nx) {
    if (blockIdx.x < (unsigned)degB) {
        int i = (blockIdx.x * 256 + threadIdx.x) * 8;
        if (i + 8 <= E) {
            int4 d0 = *(const int4*)&dst[i];
            int4 d1 = *(const int4*)&dst[i + 4];
            atomicAdd(&deg[d0.x], 1); atomicAdd(&deg[d0.y], 1);
            atomicAdd(&deg[d0.z], 1); atomicAdd(&deg[d0.w], 1);
            atomicAdd(&deg[d1.x], 1); atomicAdd(&deg[d1.y], 1);
            atomicAdd(&deg[d1.z], 1); atomicAdd(&deg[d1.w], 1);
        } else {
            for (int j = i; j < E; ++j) atomicAdd(&deg[dst[j]], 1);
        }
    } else {
        int i = (blockIdx.x - degB) * 1024 + threadIdx.x * 4;
        if (i < nx) {
            float4 v = *(const float4*)&x[i];
            __half2 h0(__float2half(v.x), __float2half(v.y));
            __half2 h1(__float2half(v.z), __float2half(v.w));
            *(__half2*)&xh[i] = h0;
            *(__half2*)&xh[i + 2] = h1;
        }
    }
}

// fused dispatch: blocks [0,nb) deg-scan + dinv; blocks [nb,..) split/transpose weights to fp16 hi/lo.
__global__ void k_scan1w(const int* __restrict__ deg, int N, int nb,
                         int* __restrict__ part, int* __restrict__ bsum, float* __restrict__ dinv,
                         const float* __restrict__ W0, __half* __restrict__ h0, __half* __restrict__ l0,
                         const float* __restrict__ W1, __half* __restrict__ h1, __half* __restrict__ l1,
                         const float* __restrict__ W2, __half* __restrict__ h2, __half* __restrict__ l2,
                         int DIN, int DH) {
    __shared__ int s[256];
    if (blockIdx.x < (unsigned)nb) {
        int i = blockIdx.x * 256 + threadIdx.x;
        int v = (i < N) ? deg[i] : 0;
        if (i < N) dinv[i] = 1.0f / sqrtf((float)(v + 1));  // +1 self-loop
        s[threadIdx.x] = v;
        __syncthreads();
        for (int off = 1; off < 256; off <<= 1) {
            int t = (threadIdx.x >= off) ? s[threadIdx.x - off] : 0;
            __syncthreads();
            s[threadIdx.x] += t;
            __syncthreads();
        }
        if (i < N) part[i] = s[threadIdx.x] - v;
        if (threadIdx.x == 255) bsum[blockIdx.x] = s[255];
    } else {
        int i = (blockIdx.x - nb) * 256 + threadIdx.x;
        const int n0 = DIN * DH, n1 = DH * DH;
        const float* W; __half *hT, *lT; int K, li;
        if (i < n0) { W = W0; hT = h0; lT = l0; K = DIN; li = i; }
        else if (i < n0 + n1) { W = W1; hT = h1; lT = l1; K = DH; li = i - n0; }
        else if (i < n0 + 2 * n1) { W = W2; hT = h2; lT = l2; K = DH; li = i - n0 - n1; }
        else return;
        int k = li / DH, n = li - k * DH;
        __half h, l;
        split2h(W[li], h, l);
        hT[(size_t)n * K + k] = h;
        lT[(size_t)n * K + k] = l;
    }
}

// rowptr build; each block reduces the raw per-block sums itself (nb <= 256).
__global__ void k_scan3(const int* __restrict__ part, const int* __restrict__ bsum, int nb,
                        int N, int E, int* __restrict__ rowptr, int* __restrict__ cursor) {
    __shared__ int s[256];
    const int t = threadIdx.x;
    s[t] = (t < nb && t < (int)blockIdx.x) ? bsum[t] : 0;
    __syncthreads();
    for (int off = 128; off > 0; off >>= 1) {
        if (t < off) s[t] += s[t + off];
        __syncthreads();
    }
    const int base = s[0];
    int i = blockIdx.x * 256 + t;
    if (i < N) {
        int v = part[i] + base;
        rowptr[i] = v;
        cursor[i] = v;
    }
    if (i == 0) rowptr[N] = E;
}

// CSR fill, 2 edges/thread.
__global__ void k_fill(const int* __restrict__ src, const int* __restrict__ dst, int E,
                       const float* __restrict__ dinv, int* __restrict__ cursor,
                       edge_t* __restrict__ edg) {
    int e = (blockIdx.x * blockDim.x + threadIdx.x) * 2;
    if (e + 2 <= E) {
        int2 s2 = *(const int2*)&src[e];
        int2 d2 = *(const int2*)&dst[e];
        int p0 = atomicAdd(&cursor[d2.x], 1);
        edge_t e0; e0.u = s2.x; e0.w = dinv[s2.x] * dinv[d2.x];
        edg[p0] = e0;
        int p1 = atomicAdd(&cursor[d2.y], 1);
        edge_t e1; e1.u = s2.y; e1.w = dinv[s2.y] * dinv[d2.y];
        edg[p1] = e1;
    } else {
        for (int j = e; j < E; ++j) {
            int s = src[j], d = dst[j];
            int p = atomicAdd(&cursor[d], 1);
            edge_t ed; ed.u = s; ed.w = dinv[s] * dinv[d];
            edg[p] = ed;
        }
    }
}

// ===================== fp16 MFMA GEMM, BN=256 (full output width per block) =============
// Block = 128 rows x 256 cols, 512 threads (8 waves, 2x4 grid of 64x64 wave tiles).
// A fetched once/layer. LDS 40KB -> 4 blocks/CU. Single-buffered (r13: dbuf neutral).

__device__ __forceinline__ void gemm_core(
    const __half* __restrict__ Aop, const __half* __restrict__ BhiT, const __half* __restrict__ BloT,
    __half* smem, int Nrows, int K, int row0,
    int wid, int lane, int wrow, int wcol, int quad, int l16, fx4 (&acc)[4][4]) {
    const __half* gp[5];
    int ldsoff[5];
#pragma unroll
    for (int j = 0; j < 5; ++j) {
        int L = wid * 5 + j;
        int arr, slot;
        if (L < 8) { arr = 0; slot = L; }
        else if (L < 24) { arr = 1; slot = L - 8; }
        else { arr = 2; slot = L - 24; }
        int r = 16 * slot + (lane >> 2);
        int s = lane & 3;
        int q = (s - (r >> 1)) & 3;              // XOR swizzle folded into global addr
        const __half* garr = (arr == 0) ? Aop : (arr == 1) ? BhiT : BloT;
        int grow = (arr == 0) ? min(row0 + r, Nrows - 1) : r;
        gp[j] = garr + (size_t)grow * K + q * 8;
        ldsoff[j] = ((arr == 0) ? 0 : (arr == 1) ? 8192 : 24576) + slot * 1024;
    }

    const __half* sA   = smem;                   // 128 x 32
    const __half* sBhi = smem + 4096;            // 256 x 32
    const __half* sBlo = smem + 12288;           // 256 x 32

    int aidx[4], bidx[4];
#pragma unroll
    for (int t = 0; t < 4; ++t) {
        int ra = wrow * 64 + t * 16 + l16;
        aidx[t] = ra * 32 + ((quad + (ra >> 1)) & 3) * 8;
        int rb = wcol * 64 + t * 16 + l16;
        bidx[t] = rb * 32 + ((quad + (rb >> 1)) & 3) * 8;
    }

    for (int k0 = 0; k0 < K; k0 += 32) {
#pragma unroll
        for (int j = 0; j < 5; ++j)
            __builtin_amdgcn_global_load_lds(AS_G(gp[j] + k0), AS_L((char*)smem + ldsoff[j]), 16, 0, 0);
        __syncthreads();

        f16x8 a[4];
#pragma unroll
        for (int mi = 0; mi < 4; ++mi) a[mi] = *(const f16x8*)&sA[aidx[mi]];
#pragma unroll
        for (int nj = 0; nj < 4; ++nj) {
            f16x8 bh = *(const f16x8*)&sBhi[bidx[nj]];
            f16x8 bl = *(const f16x8*)&sBlo[bidx[nj]];
#pragma unroll
            for (int mi = 0; mi < 4; ++mi) {
                acc[mi][nj] = __builtin_amdgcn_mfma_f32_16x16x32_f16(a[mi], bh, acc[mi][nj], 0, 0, 0);
                acc[mi][nj] = __builtin_amdgcn_mfma_f32_16x16x32_f16(a[mi], bl, acc[mi][nj], 0, 0, 0);
            }
        }
        __syncthreads();
    }
}

__global__ __launch_bounds__(512) void k_gemm_mfma(
    const __half* __restrict__ Aop, const __half* __restrict__ BhiT, const __half* __restrict__ BloT,
    const float* __restrict__ bias, __half* __restrict__ C, int Nrows, int K) {
    __shared__ __align__(16) __half smem[20480];   // 40 KB
    const int tid = threadIdx.x;
    const int wid = tid >> 6, lane = tid & 63;
    const int row0 = blockIdx.x * 128;
    const int wrow = wid & 1, wcol = wid >> 1;
    const int quad = lane >> 4, l16 = lane & 15;

    fx4 acc[4][4] = {};
    gemm_core(Aop, BhiT, BloT, smem, Nrows, K, row0, wid, lane, wrow, wcol, quad, l16, acc);

    // C/D layout: col = lane&15, row = quad*4 + reg  [m89-verified]
#pragma unroll
    for (int mi = 0; mi < 4; ++mi) {
        const int rbase = row0 + wrow * 64 + mi * 16 + quad * 4;
#pragma unroll
        for (int nj = 0; nj < 4; ++nj) {
            const int c = wcol * 64 + nj * 16 + l16;
            const float bc = bias[c];
#pragma unroll
            for (int reg = 0; reg < 4; ++reg) {
                int r = rbase + reg;
                if (r < Nrows) C[(size_t)r * 256 + c] = __float2half(fmaxf(acc[mi][nj][reg] + bc, 0.f));
            }
        }
    }
}

// Layer-2 variant: relu(acc+bias) pooled per-graph into gsum[64][256]
__global__ __launch_bounds__(512) void k_gemm_pool(
    const __half* __restrict__ Aop, const __half* __restrict__ BhiT, const __half* __restrict__ BloT,
    const float* __restrict__ bias, const int* __restrict__ batch,
    float* __restrict__ gsum, int Nrows, int K) {
    __shared__ __align__(16) __half smem[20480];
    const int tid = threadIdx.x;
    const int wid = tid >> 6, lane = tid & 63;
    const int row0 = blockIdx.x * 128;
    const int wrow = wid & 1, wcol = wid >> 1;
    const int quad = lane >> 4, l16 = lane & 15;

    fx4 acc[4][4] = {};
    gemm_core(Aop, BhiT, BloT, smem, Nrows, K, row0, wid, lane, wrow, wcol, quad, l16, acc);

    int bg[4][4];
#pragma unroll
    for (int mi = 0; mi < 4; ++mi)
#pragma unroll
        for (int reg = 0; reg < 4; ++reg) {
            int r = row0 + wrow * 64 + mi * 16 + quad * 4 + reg;
            bg[mi][reg] = (r < Nrows) ? batch[r] : -1;
        }
    const int gfirst = batch[row0 < Nrows ? row0 : (Nrows - 1)];
    const int glast  = batch[min(row0 + 127, Nrows - 1)];

#pragma unroll
    for (int nj = 0; nj < 4; ++nj) {
        const int c = wcol * 64 + nj * 16 + l16;
        const float bc = bias[c];
        for (int g = gfirst; g <= glast; ++g) {
            float s = 0.f;
#pragma unroll
            for (int mi = 0; mi < 4; ++mi)
#pragma unroll
                for (int reg = 0; reg < 4; ++reg)
                    if (bg[mi][reg] == g) s += fmaxf(acc[mi][nj][reg] + bc, 0.f);
            s += __shfl_xor(s, 16);
            s += __shfl_xor(s, 32);
            if (quad == 0) atomicAdd(&gsum[g * 256 + c], s);
        }
    }
}

// ===================== aggregation (fp16 gather, fp32 accumulate, fp16 out) =============
// WAVE-PER-NODE, straight 8-deep unroll (REVERTED from r17 edge-prefetch: the
// register double-buffer raised VGPR 32->44 and cut occupancy 60->38%, costing
// 10us/dispatch — minimal-VGPR + implicit wave overlap is the proven optimum).

__global__ __launch_bounds__(256) void k_agg256(const __half* __restrict__ H, const int* __restrict__ rowptr,
                                                const edge_t* __restrict__ edg,
                                                const float* __restrict__ dinv,
                                                __half* __restrict__ outA, int N) {
    const int wave = threadIdx.x >> 6, lane = threadIdx.x & 63;
    const int v = blockIdx.x * 4 + wave;
    if (v >= N) return;

    const float di = dinv[v];
    const float selfn = di * di;
    half4 hv = ((const half4*)&H[(size_t)v * 256])[lane];
    float2 s0 = __half22float2(hv.lo), s1 = __half22float2(hv.hi);
    float ax = selfn * s0.x, ay = selfn * s0.y, az = selfn * s1.x, aw = selfn * s1.y;

    int e = rowptr[v];
    const int end = rowptr[v + 1];
    for (; e + 8 <= end; e += 8) {
        edge_t ed[8]; half4 g[8];
#pragma unroll
        for (int j = 0; j < 8; ++j) ed[j] = edg[e + j];
#pragma unroll
        for (int j = 0; j < 8; ++j) g[j] = ((const half4*)&H[(size_t)ed[j].u * 256])[lane];
#pragma unroll
        for (int j = 0; j < 8; ++j) {
            float2 f0 = __half22float2(g[j].lo), f1 = __half22float2(g[j].hi);
            ax += ed[j].w * f0.x; ay += ed[j].w * f0.y; az += ed[j].w * f1.x; aw += ed[j].w * f1.y;
        }
    }
    for (; e < end; ++e) {
        edge_t ed = edg[e];
        half4 g = ((const half4*)&H[(size_t)ed.u * 256])[lane];
        float2 f0 = __half22float2(g.lo), f1 = __half22float2(g.hi);
        ax += ed.w * f0.x; ay += ed.w * f0.y; az += ed.w * f1.x; aw += ed.w * f1.y;
    }

    half4 o;
    o.lo = __floats2half2_rn(ax, ay);
    o.hi = __floats2half2_rn(az, aw);
    ((half4*)outA)[(size_t)v * 64 + lane] = o;
}

__global__ __launch_bounds__(256) void k_agg128(const __half* __restrict__ X, const int* __restrict__ rowptr,
                                                const edge_t* __restrict__ edg,
                                                const float* __restrict__ dinv,
                                                __half* __restrict__ outA, int N) {
    const int half = threadIdx.x >> 5, sub = threadIdx.x & 31;
    const int v = blockIdx.x * 8 + half;
    if (v >= N) return;

    const float di = dinv[v];
    const float selfn = di * di;
    half4 hv = ((const half4*)&X[(size_t)v * 128])[sub];
    float2 s0 = __half22float2(hv.lo), s1 = __half22float2(hv.hi);
    float ax = selfn * s0.x, ay = selfn * s0.y, az = selfn * s1.x, aw = selfn * s1.y;

    int e = rowptr[v];
    const int end = rowptr[v + 1];
    for (; e + 4 <= end; e += 4) {
        edge_t ed[4]; half4 g[4];
#pragma unroll
        for (int j = 0; j < 4; ++j) ed[j] = edg[e + j];
#pragma unroll
        for (int j = 0; j < 4; ++j) g[j] = ((const half4*)&X[(size_t)ed[j].u * 128])[sub];
#pragma unroll
        for (int j = 0; j < 4; ++j) {
            float2 f0 = __half22float2(g[j].lo), f1 = __half22float2(g[j].hi);
            ax += ed[j].w * f0.x; ay += ed[j].w * f0.y; az += ed[j].w * f1.x; aw += ed[j].w * f1.y;
        }
    }
    for (; e < end; ++e) {
        edge_t ed = edg[e];
        half4 g = ((const half4*)&X[(size_t)ed.u * 128])[sub];
        float2 f0 = __half22float2(g.lo), f1 = __half22float2(g.hi);
        ax += ed.w * f0.x; ay += ed.w * f0.y; az += ed.w * f1.x; aw += ed.w * f1.y;
    }

    half4 o;
    o.lo = __floats2half2_rn(ax, ay);
    o.hi = __floats2half2_rn(az, aw);
    ((half4*)outA)[(size_t)v * 32 + sub] = o;
}

// ===================== fused mean-pool finalize + classifier head =====================

__global__ __launch_bounds__(256) void k_poolcls(const float* __restrict__ gsum, const int* __restrict__ batch,
                                                 int N,
                                                 const float* __restrict__ Wc1, const float* __restrict__ bc1,
                                                 const float* __restrict__ Wc2, const float* __restrict__ bc2,
                                                 float* __restrict__ out) {
    __shared__ float sg[256], sh[256];
    __shared__ int bounds[2];
    const int b = blockIdx.x, t = threadIdx.x;
    if (t < 2) {
        int target = b + t;
        int lo = 0, hi = N;
        while (lo < hi) {
            int mid = (lo + hi) >> 1;
            if (batch[mid] < target) lo = mid + 1; else hi = mid;
        }
        bounds[t] = lo;
    }
    __syncthreads();
    const float c = (float)(bounds[1] - bounds[0]);
    sg[t] = gsum[b * 256 + t] / fmaxf(c, 1.0f);
    __syncthreads();
    float acc = bc1[t];
    for (int k = 0; k < 256; ++k) acc += sg[k] * Wc1[k * 256 + t];
    sh[t] = fmaxf(acc, 0.f);
    __syncthreads();
    if (t < 5) {
        float o = bc2[t];
        for (int k = 0; k < 256; ++k) o += sh[k] * Wc2[k * 5 + t];
        out[b * 5 + t] = o;
    }
}

// ===================== launch =====================

extern "C" void kernel_launch(void* const* d_in, const int* in_sizes, int n_in,
                              void* d_out, int out_size, void* d_ws, size_t ws_size,
                              hipStream_t stream) {
    const float* x    = (const float*)d_in[0];
    const int*   eidx = (const int*)d_in[1];
    const int*   batch= (const int*)d_in[2];
    const float* W0 = (const float*)d_in[3];  const float* b0 = (const float*)d_in[4];
    const float* W1 = (const float*)d_in[5];  const float* b1 = (const float*)d_in[6];
    const float* W2 = (const float*)d_in[7];  const float* b2 = (const float*)d_in[8];
    const float* Wc1= (const float*)d_in[9];  const float* bc1= (const float*)d_in[10];
    const float* Wc2= (const float*)d_in[11]; const float* bc2= (const float*)d_in[12];
    float* out = (float*)d_out;

    const int N   = in_sizes[2];       // 50000
    const int E   = in_sizes[1] / 2;   // 500000
    const int DIN = in_sizes[0] / N;   // 128
    const int DH  = in_sizes[4];       // 256
    const int* src = eidx;
    const int* dst = eidx + E;

    char* p = (char*)d_ws;
    auto alloc = [&](size_t bytes) {
        char* r = p;
        p += (bytes + 255) & ~(size_t)255;
        return (void*)r;
    };
    __half* hbuf = (__half*)alloc((size_t)N * DH * 2);   // gemm out (fp16), agg gather in
    __half* ha   = (__half*)alloc((size_t)N * DH * 2);   // agg out / gemm A in (fp16)
    __half* xh   = (__half*)alloc((size_t)N * DIN * 2);  // x in fp16
    __half* w0hi = (__half*)alloc((size_t)DH * DIN * 2);
    __half* w0lo = (__half*)alloc((size_t)DH * DIN * 2);
    __half* w1hi = (__half*)alloc((size_t)DH * DH * 2);
    __half* w1lo = (__half*)alloc((size_t)DH * DH * 2);
    __half* w2hi = (__half*)alloc((size_t)DH * DH * 2);
    __half* w2lo = (__half*)alloc((size_t)DH * DH * 2);
    int*   deg   = (int*)alloc((size_t)N * 4);
    float* gsum  = (float*)alloc(64 * (size_t)DH * 4);   // adjacent to deg: one memset covers both
    float* dinv  = (float*)alloc((size_t)N * 4);
    int*   part  = (int*)alloc((size_t)N * 4);
    int*   bsum  = (int*)alloc(256 * 4);
    int*   rowptr= (int*)alloc((size_t)(N + 1) * 4);
    int*   cursor= (int*)alloc((size_t)N * 4);
    edge_t* edg  = (edge_t*)alloc((size_t)E * 8);

    hipMemsetAsync(deg, 0, (size_t)((char*)gsum - (char*)deg) + 64 * (size_t)DH * 4, stream);

    const int nb = (N + 255) / 256;
    const int wtot = DIN * DH + 2 * DH * DH;
    const int wb = (wtot + 255) / 256;
    const int degB = (E + 2047) / 2048;
    const int nx = N * DIN;
    const int xb = (nx + 1023) / 1024;

    k_degx  <<<degB + xb, 256, 0, stream>>>(dst, E, deg, degB, x, xh, nx);
    k_scan1w<<<nb + wb, 256, 0, stream>>>(deg, N, nb, part, bsum, dinv,
                                          W0, w0hi, w0lo, W1, w1hi, w1lo, W2, w2hi, w2lo, DIN, DH);
    k_scan3 <<<nb, 256, 0, stream>>>(part, bsum, nb, N, E, rowptr, cursor);
    k_fill  <<<(E / 2 + 255) / 256, 256, 0, stream>>>(src, dst, E, dinv, cursor, edg);

    const int gemmBlocks = (N + 127) / 128;

    // layer 0: agg(x fp16) -> fp16 A -> gemm(relu(.W0+b0)) -> fp16 H
    k_agg128<<<(N + 7) / 8, 256, 0, stream>>>(xh, rowptr, edg, dinv, ha, N);
    k_gemm_mfma<<<gemmBlocks, 512, 0, stream>>>(ha, w0hi, w0lo, b0, hbuf, N, DIN);
    // layer 1
    k_agg256<<<(N + 3) / 4, 256, 0, stream>>>(hbuf, rowptr, edg, dinv, ha, N);
    k_gemm_mfma<<<gemmBlocks, 512, 0, stream>>>(ha, w1hi, w1lo, b1, hbuf, N, DH);
    // layer 2 (fused pooling epilogue)
    k_agg256<<<(N + 3) / 4, 256, 0, stream>>>(hbuf, rowptr, edg, dinv, ha, N);
    k_gemm_pool<<<gemmBlocks, 512, 0, stream>>>(ha, w2hi, w2lo, b2, batch, gsum, N, DH);

    k_poolcls<<<64, 256, 0, stream>>>(gsum, batch, N, Wc1, bc1, Wc2, bc2, out);
}